// Round 15
// baseline (83.240 us; speedup 1.0000x reference)
//
#include <hip/hip_runtime.h>

#define EPSF 1e-7f

typedef unsigned int u32;

// ---- DPP cross-lane helpers (VALU pipe, no DS; verified R2-R14) ----
#define DPPF0(x, ctrl) \
    __int_as_float(__builtin_amdgcn_update_dpp(0, __float_as_int(x), ctrl, 0xF, 0xF, false))

__device__ __forceinline__ float f_rcp(float x) { return __builtin_amdgcn_rcpf(x); }
__device__ __forceinline__ float wave_shr1_f(float x) { return DPPF0(x, 0x138); }

__device__ __forceinline__ float wave_max64(float x) {
    x = fmaxf(x, DPPF0(x, 0x111));
    x = fmaxf(x, DPPF0(x, 0x112));
    x = fmaxf(x, DPPF0(x, 0x114));
    x = fmaxf(x, DPPF0(x, 0x118));
    x = fmaxf(x, DPPF0(x, 0x142));
    x = fmaxf(x, DPPF0(x, 0x143));
    return __int_as_float(__builtin_amdgcn_readlane(__float_as_int(x), 63));
}

__device__ __forceinline__ float wave_sum64(float x) {
    x += DPPF0(x, 0x111);
    x += DPPF0(x, 0x112);
    x += DPPF0(x, 0x114);
    x += DPPF0(x, 0x118);
    x += DPPF0(x, 0x142);
    x += DPPF0(x, 0x143);
    return __int_as_float(__builtin_amdgcn_readlane(__float_as_int(x), 63));
}

// pack two fp32 -> bf16x2 word (RNE); unpack = shift / and (verified R13)
__device__ __forceinline__ u32 pack_bf2(float a, float b) {
    u32 ua = __float_as_uint(a), ub = __float_as_uint(b);
    ua += 0x7FFFu + ((ua >> 16) & 1u);
    ub += 0x7FFFu + ((ub >> 16) & 1u);
    return (ua >> 16) | (ub & 0xFFFF0000u);
}

// =====================================================================
// Kernel 1: pack. One block (8 waves) per batch row. Stream y_pred
// through a ping-pong LDS stage (coalesced float4 loads), LDS-gather the
// per-scan-lane label probs, q = (p+eps)/(pb+eps) packed bf16x2 ->
// pk[b][t][lane] (coalesced store); blank prob -> pbf[b][t]. One
// __syncthreads per 32-row chunk. Full chip occupancy for all TA work.
// =====================================================================
__global__ __launch_bounds__(512, 1) void ctc_pack512c(
        const int* __restrict__ y_true, const float* __restrict__ y_pred,
        u32* __restrict__ pk, float* __restrict__ pbf) {
    __shared__ float stage[2][32][128];   // 32 KB ping-pong

    const int b    = blockIdx.x;
    const int tid  = threadIdx.x;         // 0..511
    const int w    = tid >> 6;            // 0..7
    const int lane = tid & 63;
    const float* __restrict__ yp = y_pred + (size_t)b * (512 * 128);

    const int2 lc = ((const int2*)(y_true + (size_t)b * 128))[lane];
    const int c1 = lc.x, c3 = lc.y;

    u32*   __restrict__ pkb  = pk  + (size_t)b * (512 * 64);
    float* __restrict__ pbfb = pbf + (size_t)b * 512;

    // thread covers float4 slots tid and tid+512 of each 32x128 chunk
    float4 r0, r1;
    {
        const float* src = yp;
        r0 = *(const float4*)(src + (size_t)(tid >> 5) * 128 + ((tid & 31) << 2));
        const int f1 = tid + 512;
        r1 = *(const float4*)(src + (size_t)(f1 >> 5) * 128 + ((f1 & 31) << 2));
        *(float4*)(&stage[0][tid >> 5][(tid & 31) << 2]) = r0;
        *(float4*)(&stage[0][f1 >> 5][(f1 & 31) << 2]) = r1;
    }
    __syncthreads();

    for (int k = 0; k < 16; ++k) {
        if (k < 15) {   // issue next chunk's loads (latency hides under gather)
            const float* src = yp + (size_t)(k + 1) * 32 * 128;
            r0 = *(const float4*)(src + (size_t)(tid >> 5) * 128 + ((tid & 31) << 2));
            const int f1 = tid + 512;
            r1 = *(const float4*)(src + (size_t)(f1 >> 5) * 128 + ((f1 & 31) << 2));
        }
        // gather chunk k: wave w handles rows 4w..4w+3
        {
            const int buf = k & 1;
            const int tb  = k * 32 + w * 4;
#pragma unroll
            for (int rr = 0; rr < 4; ++rr) {
                const int r = w * 4 + rr;
                const float p1  = stage[buf][r][c1];
                const float p3  = stage[buf][r][c3];
                const float pb  = stage[buf][r][127];
                const float rpb = f_rcp(pb + EPSF);
                pkb[(size_t)(tb + rr) * 64 + lane] =
                    pack_bf2((p1 + EPSF) * rpb, (p3 + EPSF) * rpb);
                if (lane == 0) pbfb[tb + rr] = pb;
            }
        }
        if (k < 15) {   // write next chunk into the other buffer
            const int nb = (k + 1) & 1;
            *(float4*)(&stage[nb][tid >> 5][(tid & 31) << 2]) = r0;
            const int f1 = tid + 512;
            *(float4*)(&stage[nb][f1 >> 5][(f1 & 31) << 2]) = r1;
        }
        __syncthreads();
    }
}

// =====================================================================
// Kernel 2: scan, TWO rows interleaved per wave (R14-verified math).
// The two independent chains fill each other's dependency stalls on the
// in-order SIMD. Coalesced global dword loads of pre-divided bf16 q's,
// explicit P/Q register double-buffer. No LDS, no barriers, no asm.
// =====================================================================

#define STEPQ2(WA_, WB_) do { \
    const u32 wa_ = (WA_), wb_ = (WB_); \
    const float q1a = __uint_as_float(wa_ << 16); \
    const float q3a = __uint_as_float(wa_ & 0xFFFF0000u); \
    const float q1b = __uint_as_float(wb_ << 16); \
    const float q3b = __uint_as_float(wb_ & 0xFFFF0000u); \
    const float n3a = wave_shr1_f(uA3); \
    const float n3b = wave_shr1_f(uB3); \
    const float t1a = fmaf(m1A, n3a, uA0 + uA1); \
    const float t1b = fmaf(m1B, n3b, uB0 + uB1); \
    const float t3a = fmaf(m3A, uA1, uA2 + uA3); \
    const float t3b = fmaf(m3B, uB1, uB2 + uB3); \
    uA4 += uA3; uB4 += uB3; \
    uA2 += uA1; uB2 += uB1; \
    uA3 = t3a * q3a; uB3 = t3b * q3b; \
    uA1 = t1a * q1a; uB1 = t1b * q1b; \
    uA0 += n3a; uB0 += n3b; \
} while (0)

#define SNAPA(RM, LM) do { \
    float mm_ = fmaxf(fmaxf(uA0, uA1), fmaxf(uA2, fmaxf(uA3, uA4))); \
    mm_ = wave_max64(mm_); RM = f_rcp(mm_); LM = __logf(mm_); } while (0)
#define SNAPB(RM, LM) do { \
    float mm_ = fmaxf(fmaxf(uB0, uB1), fmaxf(uB2, fmaxf(uB3, uB4))); \
    mm_ = wave_max64(mm_); RM = f_rcp(mm_); LM = __logf(mm_); } while (0)
#define APPLYA(RM, LM) do { uA0*=RM; uA1*=RM; uA2*=RM; uA3*=RM; uA4*=RM; OA += LM; } while (0)
#define APPLYB(RM, LM) do { uB0*=RM; uB1*=RM; uB2*=RM; uB3*=RM; uB4*=RM; OB += LM; } while (0)

// load one 8-row window of q-words for both rows (coalesced global dwords)
#define LDW2G(X, BASE) do { \
    X##a0 = pkA[(size_t)((BASE)+0)*64 + lane]; X##b0 = pkB[(size_t)((BASE)+0)*64 + lane]; \
    X##a1 = pkA[(size_t)((BASE)+1)*64 + lane]; X##b1 = pkB[(size_t)((BASE)+1)*64 + lane]; \
    X##a2 = pkA[(size_t)((BASE)+2)*64 + lane]; X##b2 = pkB[(size_t)((BASE)+2)*64 + lane]; \
    X##a3 = pkA[(size_t)((BASE)+3)*64 + lane]; X##b3 = pkB[(size_t)((BASE)+3)*64 + lane]; \
    X##a4 = pkA[(size_t)((BASE)+4)*64 + lane]; X##b4 = pkB[(size_t)((BASE)+4)*64 + lane]; \
    X##a5 = pkA[(size_t)((BASE)+5)*64 + lane]; X##b5 = pkB[(size_t)((BASE)+5)*64 + lane]; \
    X##a6 = pkA[(size_t)((BASE)+6)*64 + lane]; X##b6 = pkB[(size_t)((BASE)+6)*64 + lane]; \
    X##a7 = pkA[(size_t)((BASE)+7)*64 + lane]; X##b7 = pkB[(size_t)((BASE)+7)*64 + lane]; \
} while (0)

// full 8-step window, R4/R13/R14 cadence: apply@2, snap@4, apply@6, snap@8
#define CONS8_2(X) do { \
    STEPQ2(X##a0, X##b0); STEPQ2(X##a1, X##b1); \
    APPLYA(rm1A, lm1A); APPLYB(rm1B, lm1B); \
    STEPQ2(X##a2, X##b2); STEPQ2(X##a3, X##b3); \
    SNAPA(rm2A, lm2A); SNAPB(rm2B, lm2B); \
    STEPQ2(X##a4, X##b4); STEPQ2(X##a5, X##b5); \
    APPLYA(rm2A, lm2A); APPLYB(rm2B, lm2B); \
    STEPQ2(X##a6, X##b6); STEPQ2(X##a7, X##b7); \
    SNAPA(rm1A, lm1A); SNAPB(rm1B, lm1B); \
} while (0)

// window 0: rows 1..7 (row 0 is the init), same bounded cadence
#define CONS0_2(X) do { \
    STEPQ2(X##a1, X##b1); STEPQ2(X##a2, X##b2); \
    APPLYA(rm1A, lm1A); APPLYB(rm1B, lm1B); \
    STEPQ2(X##a3, X##b3); STEPQ2(X##a4, X##b4); \
    SNAPA(rm2A, lm2A); SNAPB(rm2B, lm2B); \
    STEPQ2(X##a5, X##b5); STEPQ2(X##a6, X##b6); \
    APPLYA(rm2A, lm2A); APPLYB(rm2B, lm2B); \
    STEPQ2(X##a7, X##b7); \
    SNAPA(rm1A, lm1A); SNAPB(rm1B, lm1B); \
} while (0)

__global__ __launch_bounds__(64, 1) void ctc_scan2r512(
        const int* __restrict__ y_true, const float* __restrict__ y_pred,
        const u32* __restrict__ pk, const float* __restrict__ pbf,
        float* __restrict__ out) {
    const int blk  = blockIdx.x;           // rows 2blk, 2blk+1
    const int lane = threadIdx.x;
    const int rA = 2 * blk, rB = 2 * blk + 1;
    const float* __restrict__ ypA = y_pred + (size_t)rA * (512 * 128);
    const float* __restrict__ ypB = y_pred + (size_t)rB * (512 * 128);
    const u32* __restrict__ pkA = pk + (size_t)rA * (512 * 64);
    const u32* __restrict__ pkB = pk + (size_t)rB * (512 * 64);

    const int2 lcA = ((const int2*)(y_true + (size_t)rA * 128))[lane];
    const int2 lcB = ((const int2*)(y_true + (size_t)rB * 128))[lane];
    const int c1A = lcA.x, c3A = lcA.y, c1B = lcB.x, c3B = lcB.y;

    const int cpA = __builtin_amdgcn_update_dpp(0, c3A, 0x138, 0xF, 0xF, false);
    const int cpB = __builtin_amdgcn_update_dpp(0, c3B, 0x138, 0xF, 0xF, false);
    const float m1A = (lane > 0 && c1A != cpA) ? 1.f : 0.f;
    const float m3A = (c3A != c1A) ? 1.f : 0.f;
    const float m1B = (lane > 0 && c1B != cpB) ? 1.f : 0.f;
    const float m3B = (c3B != c1B) ? 1.f : 0.f;

    // blank log-sums over rows 1..511, wave-parallel (R12-verified pattern)
    float blsA = 0.f, blsB = 0.f;
    {
        const float* pA = pbf + (size_t)rA * 512 + lane * 8;
        const float* pB = pbf + (size_t)rB * 512 + lane * 8;
        const float4 a0 = *(const float4*)(pA);
        const float4 a1 = *(const float4*)(pA + 4);
        const float4 b0 = *(const float4*)(pB);
        const float4 b1 = *(const float4*)(pB + 4);
        float sa = __logf(a0.y + EPSF) + __logf(a0.z + EPSF) + __logf(a0.w + EPSF)
                 + __logf(a1.x + EPSF) + __logf(a1.y + EPSF) + __logf(a1.z + EPSF)
                 + __logf(a1.w + EPSF);
        float sb = __logf(b0.y + EPSF) + __logf(b0.z + EPSF) + __logf(b0.w + EPSF)
                 + __logf(b1.x + EPSF) + __logf(b1.y + EPSF) + __logf(b1.z + EPSF)
                 + __logf(b1.w + EPSF);
        if (lane > 0) { sa += __logf(a0.x + EPSF); sb += __logf(b0.x + EPSF); }
        blsA = wave_sum64(sa);
        blsB = wave_sum64(sb);
    }

    // init from row 0 (exact fp32)
    float uA0 = (lane == 0) ? ypA[127] + EPSF : 0.f;
    float uA1 = (lane == 0) ? ypA[c1A] + EPSF : 0.f;
    float uA2 = 0.f, uA3 = 0.f, uA4 = 0.f;
    float uB0 = (lane == 0) ? ypB[127] + EPSF : 0.f;
    float uB1 = (lane == 0) ? ypB[c1B] + EPSF : 0.f;
    float uB2 = 0.f, uB3 = 0.f, uB4 = 0.f;
    float OA = 0.f, OB = 0.f;
    float rm1A = 1.f, lm1A = 0.f, rm2A = 1.f, lm2A = 0.f;
    float rm1B = 1.f, lm1B = 0.f, rm2B = 1.f, lm2B = 0.f;

    u32 Pa0, Pa1, Pa2, Pa3, Pa4, Pa5, Pa6, Pa7;
    u32 Pb0, Pb1, Pb2, Pb3, Pb4, Pb5, Pb6, Pb7;
    u32 Qa0, Qa1, Qa2, Qa3, Qa4, Qa5, Qa6, Qa7;
    u32 Qb0, Qb1, Qb2, Qb3, Qb4, Qb5, Qb6, Qb7;

    LDW2G(P, 0);                     // W0 (rows 0..7)
    LDW2G(Q, 8);                     // W1 prefetch
    CONS0_2(P);                      // steps: rows 1..7

    for (int j = 0; j < 31; ++j) {
        LDW2G(P, 16 * j + 16); CONS8_2(Q);   // consume W(2j+1), prefetch W(2j+2)
        LDW2G(Q, 16 * j + 24); CONS8_2(P);   // consume W(2j+2), prefetch W(2j+3)
    }
    CONS8_2(Q);                      // W63 (rows 504..511)

    if (lane == 63) {
        out[rA] = -(OA + blsA + __logf(uA3 + uA4));
        out[rB] = -(OB + blsB + __logf(uB3 + uB4));
    }
}

// =====================================================================
// Fallback: R8 kernel (passed, 41 µs) for ws-too-small; generic for
// other shapes.
// =====================================================================
#define SB0() __builtin_amdgcn_sched_barrier(0)
#define WAITV(N) do { asm volatile("s_waitcnt vmcnt(" #N ")" ::: "memory"); SB0(); } while (0)
#define ISS(dst, voff, IMM) \
    asm volatile("global_load_dword %0, %1, %2 offset:" #IMM \
                 : "=v"(dst) : "v"(voff), "s"(pn))
#define GISSUE(X) do { \
    ISS(X##b[0], vb, 0);    ISS(X##1[0], v1, 0);    ISS(X##3[0], v3, 0); \
    ISS(X##b[1], vb, 512);  ISS(X##1[1], v1, 512);  ISS(X##3[1], v3, 512); \
    ISS(X##b[2], vb, 1024); ISS(X##1[2], v1, 1024); ISS(X##3[2], v3, 1024); \
    ISS(X##b[3], vb, 1536); ISS(X##1[3], v1, 1536); ISS(X##3[3], v3, 1536); \
    ISS(X##b[4], vb, 2048); ISS(X##1[4], v1, 2048); ISS(X##3[4], v3, 2048); \
    ISS(X##b[5], vb, 2560); ISS(X##1[5], v1, 2560); ISS(X##3[5], v3, 2560); \
    ISS(X##b[6], vb, 3072); ISS(X##1[6], v1, 3072); ISS(X##3[6], v3, 3072); \
    ISS(X##b[7], vb, 3584); ISS(X##1[7], v1, 3584); ISS(X##3[7], v3, 3584); \
    pn += 8 * 128; \
} while (0)
#define GISSUE_T7(X) do { \
    ISS(X##b[0], vb, 0);    ISS(X##1[0], v1, 0);    ISS(X##3[0], v3, 0); \
    ISS(X##b[1], vb, 512);  ISS(X##1[1], v1, 512);  ISS(X##3[1], v3, 512); \
    ISS(X##b[2], vb, 1024); ISS(X##1[2], v1, 1024); ISS(X##3[2], v3, 1024); \
    ISS(X##b[3], vb, 1536); ISS(X##1[3], v1, 1536); ISS(X##3[3], v3, 1536); \
    ISS(X##b[4], vb, 2048); ISS(X##1[4], v1, 2048); ISS(X##3[4], v3, 2048); \
    ISS(X##b[5], vb, 2560); ISS(X##1[5], v1, 2560); ISS(X##3[5], v3, 2560); \
    ISS(X##b[6], vb, 3072); ISS(X##1[6], v1, 3072); ISS(X##3[6], v3, 3072); \
} while (0)
#define PSTEP(PBE_, P1_, P3_) do { \
    const float e1 = (P1_) + EPSF; \
    const float e3 = (P3_) + EPSF; \
    const float n3 = wave_shr1_f(u3); \
    const float t1 = fmaf(m1, n3, u0 + u1); \
    const float t3 = fmaf(m3, u1, u2 + u3); \
    u4 = (u4 + u3) * (PBE_); \
    u3 = t3 * e3; \
    u2 = (u2 + u1) * (PBE_); \
    u1 = t1 * e1; \
    u0 = (u0 + n3) * (PBE_); \
} while (0)
#define SNAP(RM, LM) do { \
    float mm_ = fmaxf(fmaxf(u0, u1), fmaxf(u2, fmaxf(u3, u4))); \
    mm_ = wave_max64(mm_); \
    RM = f_rcp(mm_); \
    LM = __logf(mm_); \
} while (0)
#define APPLY(RM, LM) do { \
    u0 *= RM; u1 *= RM; u2 *= RM; u3 *= RM; u4 *= RM; \
    O += LM; \
} while (0)
#define PBED(X, k) const float pbe##k = X##b[k] + EPSF;
#define CONS8(X) do { \
    PBED(X,0) PBED(X,1) PBED(X,2) PBED(X,3) PBED(X,4) PBED(X,5) PBED(X,6) PBED(X,7) \
    PSTEP(pbe0, X##1[0], X##3[0]); \
    PSTEP(pbe1, X##1[1], X##3[1]); \
    APPLY(rmA, lmA); \
    PSTEP(pbe2, X##1[2], X##3[2]); \
    PSTEP(pbe3, X##1[3], X##3[3]); \
    SNAP(rmB, lmB); \
    PSTEP(pbe4, X##1[4], X##3[4]); \
    PSTEP(pbe5, X##1[5], X##3[5]); \
    APPLY(rmB, lmB); \
    PSTEP(pbe6, X##1[6], X##3[6]); \
    PSTEP(pbe7, X##1[7], X##3[7]); \
    SNAP(rmA, lmA); \
} while (0)
#define CONS_T7(X) do { \
    PBED(X,0) PBED(X,1) PBED(X,2) PBED(X,3) PBED(X,4) PBED(X,5) PBED(X,6) \
    PSTEP(pbe0, X##1[0], X##3[0]); \
    PSTEP(pbe1, X##1[1], X##3[1]); \
    APPLY(rmA, lmA); \
    PSTEP(pbe2, X##1[2], X##3[2]); \
    PSTEP(pbe3, X##1[3], X##3[3]); \
    SNAP(rmB, lmB); \
    PSTEP(pbe4, X##1[4], X##3[4]); \
    PSTEP(pbe5, X##1[5], X##3[5]); \
    APPLY(rmB, lmB); \
    PSTEP(pbe6, X##1[6], X##3[6]); \
} while (0)

__global__ __launch_bounds__(64, 1) void ctc_prod512(
        const int* __restrict__ y_true, const float* __restrict__ y_pred,
        float* __restrict__ out) {
    const int b    = blockIdx.x;
    const int lane = threadIdx.x;
    const float* __restrict__ yp = y_pred + (size_t)b * (512 * 128);

    const int2 lc = ((const int2*)(y_true + (size_t)b * 128))[lane];
    const int c1 = lc.x, c3 = lc.y;
    const int cp = __builtin_amdgcn_update_dpp(0, c3, 0x138, 0xF, 0xF, false);
    const float m1 = (lane > 0 && c1 != cp) ? 1.f : 0.f;
    const float m3 = (c3 != c1) ? 1.f : 0.f;

    float u0, u1, u2 = 0.f, u3 = 0.f, u4 = 0.f;
    {
        const float pvb = yp[127];
        const float pv1 = yp[c1];
        u0 = (lane == 0) ? pvb + EPSF : 0.f;
        u1 = (lane == 0) ? pv1 + EPSF : 0.f;
    }
    float O = 0.f;
    float rmA = 1.0f, lmA = 0.0f, rmB = 1.0f, lmB = 0.0f;

    const int vb = 127 * 4;
    const int v1 = c1 * 4;
    const int v3 = c3 * 4;
    const float* pn = yp + 128;

    WAITV(0);

    float Ab[8], A1[8], A3[8];
    float Bb[8], B1[8], B3[8];
    float Cb[8], C1[8], C3[8];

    GISSUE(A);
    GISSUE(B);

    for (int j = 0; j < 20; ++j) {
        WAITV(24); GISSUE(C); CONS8(A);
        WAITV(24); GISSUE(A); CONS8(B);
        WAITV(24); GISSUE(B); CONS8(C);
    }
    WAITV(24); GISSUE(C);    CONS8(A);
    WAITV(24); GISSUE_T7(A); CONS8(B);
    WAITV(21); CONS8(C);
    WAITV(0);  CONS_T7(A);

    if (lane == 63) out[b] = -(O + __logf(u3 + u4));
}

__global__ __launch_bounds__(64, 1) void ctc_scan_generic(
        const int* __restrict__ y_true, const float* __restrict__ y_pred,
        float* __restrict__ out, int T, int C, int U) {
    const int b    = blockIdx.x;
    const int lane = threadIdx.x;
    const int blank = C - 1;
    const float* __restrict__ yp = y_pred + (size_t)b * T * C;

    const int2 lc = ((const int2*)(y_true + (size_t)b * U))[lane];
    const int c1 = lc.x, c3 = lc.y;
    const int cp = __builtin_amdgcn_update_dpp(0, c3, 0x138, 0xF, 0xF, false);
    const float m1 = (lane > 0 && c1 != cp) ? 1.f : 0.f;
    const float m3 = (c3 != c1) ? 1.f : 0.f;

    float u0 = (lane == 0) ? yp[blank] + EPSF : 0.f;
    float u1 = (lane == 0) ? yp[c1] + EPSF : 0.f;
    float u2 = 0.f, u3 = 0.f, u4 = 0.f;
    float O = 0.f;
    float rmA = 1.0f, lmA = 0.0f;
    int kren = 0;

    for (int t = 1; t < T; ++t) {
        const float* row = yp + (size_t)t * C;
        const float pbe = row[blank] + EPSF;
        const float rpb = f_rcp(pbe);
        const float q1  = (row[c1] + EPSF) * rpb;
        const float q3  = (row[c3] + EPSF) * rpb;
        const float n3  = wave_shr1_f(u3);
        const float t1  = fmaf(m1, n3, u0 + u1);
        const float t3  = fmaf(m3, u1, u2 + u3);
        u4 = u4 + u3;
        u3 = t3 * q3;
        u2 = u2 + u1;
        u1 = t1 * q1;
        u0 = u0 + n3;
        O += __logf(pbe);
        if (++kren == 4) {
            SNAP(rmA, lmA);
            APPLY(rmA, lmA);
            kren = 0;
        }
    }
    if (lane == 63) out[b] = -(O + __logf(u3 + u4));
}

extern "C" void kernel_launch(void* const* d_in, const int* in_sizes, int n_in,
                              void* d_out, int out_size, void* d_ws, size_t ws_size,
                              hipStream_t stream) {
    const int*   y_true = (const int*)d_in[0];
    const float* y_pred = (const float*)d_in[1];
    float*       out    = (float*)d_out;

    const int B = out_size;                 // 256
    const int U = in_sizes[0] / B;          // 128
    const int C = 128;                      // classes incl. blank
    const int T = in_sizes[1] / (B * C);    // 512

    if (T == 512 && C == 128 && U == 128 && (B & 1) == 0) {
        const size_t pk_bytes = (size_t)B * 512 * 64 * 4;   // 33.5 MB @ B=256
        const size_t need     = pk_bytes + (size_t)B * 512 * 4;
        if (ws_size >= need) {
            u32*   pkw = (u32*)d_ws;
            float* pbf = (float*)((char*)d_ws + pk_bytes);
            ctc_pack512c<<<B, 512, 0, stream>>>(y_true, y_pred, pkw, pbf);
            ctc_scan2r512<<<B / 2, 64, 0, stream>>>(y_true, y_pred, pkw, pbf, out);
        } else {
            ctc_prod512<<<B, 64, 0, stream>>>(y_true, y_pred, out);
        }
    } else {
        ctc_scan_generic<<<B, 64, 0, stream>>>(y_true, y_pred, out, T, C, U);
    }
}

// Round 16
// 53.851 us; speedup vs baseline: 1.5458x; 1.5458x over previous
//
#include <hip/hip_runtime.h>

#define EPSF 1e-7f

typedef unsigned int u32;

// ---- DPP cross-lane helpers (VALU pipe, no DS; verified R2-R15) ----
#define DPPF0(x, ctrl) \
    __int_as_float(__builtin_amdgcn_update_dpp(0, __float_as_int(x), ctrl, 0xF, 0xF, false))

__device__ __forceinline__ float f_rcp(float x) { return __builtin_amdgcn_rcpf(x); }
__device__ __forceinline__ float wave_shr1_f(float x) { return DPPF0(x, 0x138); }

__device__ __forceinline__ float wave_max64(float x) {
    x = fmaxf(x, DPPF0(x, 0x111));   // row_shr:1
    x = fmaxf(x, DPPF0(x, 0x112));   // row_shr:2
    x = fmaxf(x, DPPF0(x, 0x114));   // row_shr:4
    x = fmaxf(x, DPPF0(x, 0x118));   // row_shr:8
    x = fmaxf(x, DPPF0(x, 0x142));   // row_bcast:15
    x = fmaxf(x, DPPF0(x, 0x143));   // row_bcast:31
    return __int_as_float(__builtin_amdgcn_readlane(__float_as_int(x), 63));
}

// pack two fp32 -> bf16x2 word (RNE); unpack = shift / and (verified R13)
__device__ __forceinline__ u32 pack_bf2(float a, float b) {
    u32 ua = __float_as_uint(a), ub = __float_as_uint(b);
    ua += 0x7FFFu + ((ua >> 16) & 1u);
    ub += 0x7FFFu + ((ub >> 16) & 1u);
    return (ua >> 16) | (ub & 0xFFFF0000u);
}

// ---- one CTC step, q-normalized bf16 pair (R13-verified, absmax 0.0) ----
#define STEPQ(W_) do { \
    const u32 w_ = (W_); \
    const float q1 = __uint_as_float(w_ << 16); \
    const float q3 = __uint_as_float(w_ & 0xFFFF0000u); \
    const float n3 = wave_shr1_f(u3); \
    const float t1 = fmaf(m1, n3, u0 + u1); \
    const float t3 = fmaf(m3, u1, u2 + u3); \
    u4 = u4 + u3; \
    u3 = t3 * q3; \
    u2 = u2 + u1; \
    u1 = t1 * q1; \
    u0 = u0 + n3; \
} while (0)

#define SNAP2(RM, LM) do { \
    float mm_ = fmaxf(fmaxf(u0, u1), fmaxf(u2, fmaxf(u3, u4))); \
    mm_ = wave_max64(mm_); \
    RM = f_rcp(mm_); \
    LM = __logf(mm_); \
} while (0)

#define APPLY2(RM, LM) do { \
    u0 *= RM; u1 *= RM; u2 *= RM; u3 *= RM; u4 *= RM; \
    O += LM; \
} while (0)

// 8 steps from q[I0..I0+7], R4/R13 cadence: apply@2, snap@4, apply@6, snap@8
#define CONS8Q(I0) do { \
    STEPQ(q[(I0)+0]); STEPQ(q[(I0)+1]); APPLY2(rm1, lm1); \
    STEPQ(q[(I0)+2]); STEPQ(q[(I0)+3]); SNAP2(rm2, lm2); \
    STEPQ(q[(I0)+4]); STEPQ(q[(I0)+5]); APPLY2(rm2, lm2); \
    STEPQ(q[(I0)+6]); STEPQ(q[(I0)+7]); SNAP2(rm1, lm1); \
} while (0)

// chunk-0 first window: steps t=1..7 (t=0 is the init), same cadence
#define CONS0Q() do { \
    STEPQ(q[1]); STEPQ(q[2]); APPLY2(rm1, lm1); \
    STEPQ(q[3]); STEPQ(q[4]); SNAP2(rm2, lm2); \
    STEPQ(q[5]); STEPQ(q[6]); APPLY2(rm2, lm2); \
    STEPQ(q[7]); SNAP2(rm1, lm1); \
} while (0)

// =====================================================================
// Barrier-free producer-consumer, T=512/C=128/U=128. One block (4 waves)
// per batch row, 256 blocks.
//   waves 1-3 (producers): gather p[c1],p[c3],pb per row, q=(p+e)/(pb+e),
//     pack bf16x2 -> LDS ring qbuf[4][64][33]; Σlog(pb) partials.
//   wave 0 (consumer): 511-step scan, R13-verified math; acquires each
//     32-step chunk via a monotonic LDS flag; never hits a barrier.
// Ring flow control: producers wait on cons_prog before reusing a slot.
// Producer gathers run on SIMDs 1-3 — entirely off the scan wave's SIMD.
// =====================================================================
__global__ __launch_bounds__(256, 1) void ctc_ring512(
        const int* __restrict__ y_true, const float* __restrict__ y_pred,
        float* __restrict__ out) {
    __shared__ u32   qbuf[4][64][33];  // 33-pad: (33*l+i)%32 distinct per l
    __shared__ int   flags[4];         // monotonic: +1 per producer per round
    __shared__ int   cons_prog;        // chunks fully consumed
    __shared__ float blsw[4];          // Σlog(pb) partials per producer wave

    const int b    = blockIdx.x;
    const int tid  = threadIdx.x;
    const int w    = tid >> 6;
    const int lane = tid & 63;
    const float* __restrict__ yp = y_pred + (size_t)b * (512 * 128);

    const int2 lc = ((const int2*)(y_true + (size_t)b * 128))[lane];
    const int c1 = lc.x, c3 = lc.y;

    if (tid < 4) flags[tid] = 0;
    if (tid == 4) cons_prog = 0;
    __syncthreads();                   // the only barrier (init)

    if (w != 0) {
        // ---------------- producers: waves 1..3 ----------------
        float bls = 0.f;
        for (int c = 0; c < 16; ++c) {
            if (c >= 4) {              // ring capacity: slot c&3 free?
                while (__hip_atomic_load(&cons_prog, __ATOMIC_ACQUIRE,
                                         __HIP_MEMORY_SCOPE_WORKGROUP) < c - 3)
                    __builtin_amdgcn_s_sleep(2);
            }
            const int s = c & 3;
#pragma unroll
            for (int k = 0; k < 11; ++k) {
                const int j = (w - 1) + 3 * k;
                if (j < 32) {
                    const int t = c * 32 + j;
                    const float* rowp = yp + (size_t)t * 128;
                    const float p1  = rowp[c1];
                    const float p3  = rowp[c3];
                    const float pbe = rowp[127] + EPSF;
                    const float rpb = f_rcp(pbe);
                    qbuf[s][lane][j] = pack_bf2((p1 + EPSF) * rpb,
                                                (p3 + EPSF) * rpb);
                    if (t >= 1) bls += __logf(pbe);  // lane-uniform
                }
            }
            if (c == 15 && lane == 0) blsw[w] = bls;   // before final release
            if (lane == 0)
                __hip_atomic_fetch_add(&flags[s], 1, __ATOMIC_RELEASE,
                                       __HIP_MEMORY_SCOPE_WORKGROUP);
        }
        return;
    }

    // ---------------- consumer: wave 0 ----------------
    const int cp = __builtin_amdgcn_update_dpp(0, c3, 0x138, 0xF, 0xF, false);
    const float m1 = (lane > 0 && c1 != cp) ? 1.f : 0.f;
    const float m3 = (c3 != c1) ? 1.f : 0.f;

    // init from row 0 (exact fp32)
    float u0 = (lane == 0) ? yp[127] + EPSF : 0.f;
    float u1 = (lane == 0) ? yp[c1] + EPSF : 0.f;
    float u2 = 0.f, u3 = 0.f, u4 = 0.f;
    float O = 0.f;
    float rm1 = 1.f, lm1 = 0.f, rm2 = 1.f, lm2 = 0.f;

    for (int c = 0; c < 16; ++c) {
        const int s = c & 3;
        const int need = 3 * ((c >> 2) + 1);
        while (__hip_atomic_load(&flags[s], __ATOMIC_ACQUIRE,
                                 __HIP_MEMORY_SCOPE_WORKGROUP) < need)
            ;  // producers are normally ahead
        u32 q[32];
#pragma unroll
        for (int i = 0; i < 32; ++i) q[i] = qbuf[s][lane][i];
        if (c == 0) { CONS0Q(); } else { CONS8Q(0); }
        CONS8Q(8);
        CONS8Q(16);
        CONS8Q(24);
        if (lane == 0)
            __hip_atomic_store(&cons_prog, c + 1, __ATOMIC_RELEASE,
                               __HIP_MEMORY_SCOPE_WORKGROUP);
    }

    // producers' bls partials are visible (released before chunk-15 flags)
    const float bls = blsw[1] + blsw[2] + blsw[3];
    if (lane == 63) out[b] = -(O + bls + __logf(u3 + u4));
}

// =====================================================================
// Generic fallback (other shapes), R12-verified.
// =====================================================================
__global__ __launch_bounds__(64, 1) void ctc_scan_generic(
        const int* __restrict__ y_true, const float* __restrict__ y_pred,
        float* __restrict__ out, int T, int C, int U) {
    const int b    = blockIdx.x;
    const int lane = threadIdx.x;
    const int blank = C - 1;
    const float* __restrict__ yp = y_pred + (size_t)b * T * C;

    const int2 lc = ((const int2*)(y_true + (size_t)b * U))[lane];
    const int c1 = lc.x, c3 = lc.y;
    const int cp = __builtin_amdgcn_update_dpp(0, c3, 0x138, 0xF, 0xF, false);
    const float m1 = (lane > 0 && c1 != cp) ? 1.f : 0.f;
    const float m3 = (c3 != c1) ? 1.f : 0.f;

    float u0 = (lane == 0) ? yp[blank] + EPSF : 0.f;
    float u1 = (lane == 0) ? yp[c1] + EPSF : 0.f;
    float u2 = 0.f, u3 = 0.f, u4 = 0.f;
    float O = 0.f;
    float rm1 = 1.0f, lm1 = 0.0f;
    int kren = 0;

    for (int t = 1; t < T; ++t) {
        const float* row = yp + (size_t)t * C;
        const float pbe = row[blank] + EPSF;
        const float rpb = f_rcp(pbe);
        const float q1  = (row[c1] + EPSF) * rpb;
        const float q3  = (row[c3] + EPSF) * rpb;
        const float n3  = wave_shr1_f(u3);
        const float t1  = fmaf(m1, n3, u0 + u1);
        const float t3  = fmaf(m3, u1, u2 + u3);
        u4 = u4 + u3;
        u3 = t3 * q3;
        u2 = u2 + u1;
        u1 = t1 * q1;
        u0 = u0 + n3;
        O += __logf(pbe);
        if (++kren == 4) {
            float mm_ = fmaxf(fmaxf(u0, u1), fmaxf(u2, fmaxf(u3, u4)));
            mm_ = wave_max64(mm_);
            rm1 = f_rcp(mm_);
            lm1 = __logf(mm_);
            u0 *= rm1; u1 *= rm1; u2 *= rm1; u3 *= rm1; u4 *= rm1;
            O += lm1;
            kren = 0;
        }
    }
    if (lane == 63) out[b] = -(O + __logf(u3 + u4));
}

extern "C" void kernel_launch(void* const* d_in, const int* in_sizes, int n_in,
                              void* d_out, int out_size, void* d_ws, size_t ws_size,
                              hipStream_t stream) {
    const int*   y_true = (const int*)d_in[0];
    const float* y_pred = (const float*)d_in[1];
    float*       out    = (float*)d_out;

    const int B = out_size;                 // 256
    const int U = in_sizes[0] / B;          // 128
    const int C = 128;                      // classes incl. blank
    const int T = in_sizes[1] / (B * C);    // 512

    if (T == 512 && C == 128 && U == 128) {
        ctc_ring512<<<B, 256, 0, stream>>>(y_true, y_pred, out);
    } else {
        ctc_scan_generic<<<B, 64, 0, stream>>>(y_true, y_pred, out, T, C, U);
    }
}